// Round 7
// baseline (165.182 us; speedup 1.0000x reference)
//
#include <hip/hip_runtime.h>
#include <cstdint>

constexpr int B  = 4;
constexpr int C  = 128;
constexpr int CM = 32;        // mid channels
constexpr int H  = 160;
constexpr int W  = 160;
constexpr int HW = H * W;     // 25600
constexpr int HP = H + 1;     // 161
constexpr int WP = W + 1;     // 161
constexpr int PLANE = HP * WP; // 25921
constexpr int TY = 16;         // rows per box tile
constexpr int NTILE = H / TY;  // 10
constexpr int PB  = 64;        // positions per conv block
constexpr int K1B = B * HW / PB; // 1600 conv blocks
constexpr int NB2 = B * NTILE; // 40 partials per out-channel
constexpr int QR = 40;         // rows per scan quarter

// ------- K1: 1x1 conv; x-tile staged in LDS (kills 4x cross-wave L2/L3 re-read) -------
__global__ __launch_bounds__(256) void k_conv(
    const float* __restrict__ x, const float* __restrict__ w1,
    float* __restrict__ h, float* __restrict__ part1)
{
    __shared__ float wT[C * CM];   // 16 KB; wT[c*CM + o]
    __shared__ float xs[C][PB];    // 32 KB; xs[c][p]
    int tid = threadIdx.x;
    for (int i = tid; i < C * CM; i += 256) {
        int o = i & (CM - 1), c = i >> 5;
        wT[i] = w1[o * C + c];
    }

    int bid = blockIdx.x;                 // 1600 blocks; 400 per batch image
    int b = bid / 400;
    int p0 = (bid % 400) * PB;
    const float* xb = x + (size_t)b * C * HW + p0;

    // stage x tile: 128 ch x 64 pos, float4-coalesced (8 iters/thread)
    for (int i = tid; i < C * PB / 4; i += 256) {
        int c = i >> 4, pp = (i & 15) * 4;
        *reinterpret_cast<float4*>(&xs[c][pp]) =
            *reinterpret_cast<const float4*>(xb + (size_t)c * HW + pp);
    }
    __syncthreads();

    int wave = tid >> 6, lane = tid & 63;
    float acc[8];
    #pragma unroll
    for (int j = 0; j < 8; ++j) acc[j] = 0.f;

    const float* wbase = &wT[wave * 8];   // this wave's 8 output channels
    #pragma unroll 8
    for (int c = 0; c < C; ++c) {
        float xv = xs[c][lane];                       // 2-way bank alias: free
        const float4* wr = reinterpret_cast<const float4*>(wbase + c * CM);
        float4 wa = wr[0], wb4 = wr[1];               // uniform addr: broadcast
        float wv[8] = {wa.x, wa.y, wa.z, wa.w, wb4.x, wb4.y, wb4.z, wb4.w};
        #pragma unroll
        for (int j = 0; j < 8; ++j) acc[j] = fmaf(wv[j], xv, acc[j]);
    }

    float* hb = h + ((size_t)(b * CM + wave * 8)) * HW + p0 + lane;
    #pragma unroll
    for (int j = 0; j < 8; ++j) {
        hb[(size_t)j * HW] = acc[j];
        float s  = acc[j];
        float s2 = acc[j] * acc[j];
        #pragma unroll
        for (int off = 32; off > 0; off >>= 1) {
            s  += __shfl_down(s,  off);
            s2 += __shfl_down(s2, off);
        }
        if (lane == 0) {
            int o = wave * 8 + j;
            part1[(size_t)o * K1B + bid]        = s;   // row o      : sums
            part1[(size_t)(o + CM) * K1B + bid] = s2;  // row CM + o : sumsq
        }
    }
}

// ---------------- R1: deterministic reduction -> BN1 scale/shift ----------------
__global__ __launch_bounds__(256) void k_reduce1(
    const float* __restrict__ part1, const float* __restrict__ g1,
    const float* __restrict__ b1, float* __restrict__ sc1)
{
    __shared__ double pr[256];
    __shared__ double dsum[2 * CM];
    int t = threadIdx.x;
    int row = t >> 2, j = t & 3;        // 64 rows x 4 threads
    double acc = 0.0;
    for (int i = j; i < K1B; i += 4) acc += (double)part1[(size_t)row * K1B + i];
    pr[t] = acc;
    __syncthreads();
    if (j == 0) dsum[row] = pr[t] + pr[t + 1] + pr[t + 2] + pr[t + 3];
    __syncthreads();
    if (t < CM) {
        double n = (double)(B * HW);
        double mean = dsum[t] / n;
        double var  = dsum[CM + t] / n - mean * mean;
        float inv   = (float)(1.0 / sqrt(var + 1e-5));
        float scale = g1[t] * inv;
        sc1[t]      = scale;
        sc1[CM + t] = b1[t] - (float)mean * scale;
    }
}

// ------- K2a: BN1+ReLU + row scan + LOCAL col scan per (plane, quarter) -------
//         also emits pre-fix local last row to qlast[plane][q] for q < 3
__global__ __launch_bounds__(256) void k_scan_part(
    const float* __restrict__ h, const float* __restrict__ sc1,
    float* __restrict__ II, float* __restrict__ qlast)
{
    __shared__ float buf[QR * W];   // 40 row-scanned rows, 25600 B
    int tid = threadIdx.x;
    int wave = tid >> 6, lane = tid & 63;
    int blk = blockIdx.x;           // plane*4 + q
    int plane = blk >> 2, q = blk & 3;
    int cm = plane & (CM - 1);

    float scale = sc1[cm];
    float shift = sc1[CM + cm];

    const float* hp = h + (size_t)plane * HW + (size_t)q * QR * W;
    float* IIp = II + (size_t)plane * PLANE;

    // top border row (quarter 0 only) — independent of buf
    if (q == 0) {
        for (int e = tid; e < WP; e += 256) IIp[e] = 0.f;
    }

    // phase 1: BN+ReLU + row inclusive scan into LDS (wave-per-row shuffle scan)
    for (int y = wave; y < QR; y += 4) {
        const float* hr = hp + (size_t)y * W;
        float carry = 0.f;
        #pragma unroll
        for (int x0 = 0; x0 < W; x0 += 64) {
            int xx = x0 + lane;
            float v = (xx < W) ? fmaxf(fmaf(scale, hr[xx], shift), 0.f) : 0.f;
            #pragma unroll
            for (int off = 1; off < 64; off <<= 1) {
                float t = __shfl_up(v, off);
                if (lane >= off) v += t;
            }
            v += carry;
            if (xx < W) buf[y * W + xx] = v;
            carry = __shfl(v, 63);
        }
    }
    __syncthreads();

    // phase 2: local column scan + write II rows q*40+1 .. q*40+40
    float* op = IIp + (size_t)(q * QR + 1) * WP;
    float* ql = qlast + ((size_t)plane * 3 + q) * WP;
    if (tid <= W) {
        float run = 0.f;
        #pragma unroll 4
        for (int r = 0; r < QR; ++r) {
            float v = 0.f;
            if (tid > 0) { run += buf[r * W + (tid - 1)]; v = run; }
            op[(size_t)r * WP + tid] = v;
            if (r == QR - 1 && q < 3) ql[tid] = v;
        }
    }
}

// ------- K2b: add cross-quarter offsets; block = (plane, chunk f of rows 41+40f..80+40f) -------
__global__ __launch_bounds__(256) void k_scan_fix(
    float* __restrict__ II, const float* __restrict__ qlast)
{
    __shared__ float off[WP];
    int tid = threadIdx.x;
    int blk = blockIdx.x;
    int plane = blk / 3, f = blk % 3;

    const float* qb = qlast + (size_t)plane * 3 * WP;
    for (int v = tid; v < WP; v += 256) {
        float s = qb[v];
        if (f >= 1) s += qb[WP + v];
        if (f >= 2) s += qb[2 * WP + v];
        off[v] = s;
    }
    __syncthreads();

    float* P = II + (size_t)plane * PLANE + (size_t)(41 + f * QR) * WP;
    constexpr int total = QR * WP;
    for (int e = tid; e < total; e += 256) {
        P[e] += off[e % WP];
    }
}

// ---------------- box tile machinery ----------------
struct BoxSmem {
    float D[TY][WP];      // row-interp difference rows
    int   ru0[2][TY];     // [0]=lo, [1]=hi row coords
    int   ru1[2][TY];
    float rua[2][TY];
    int   cv0[2][W];      // col coords ([0]=lo, [1]=hi)
    float cva[2][W];
};

__device__ inline void fill_D(BoxSmem& sm, const float* __restrict__ II,
    int tile, int k, int b,
    const float* __restrict__ xmin, const float* __restrict__ xmax,
    const float* __restrict__ ymin, const float* __restrict__ ymax)
{
    int tid = threadIdx.x;
    if (tid < 2 * TY) {
        int side = tid / TY, ty = tid % TY;
        float off = side ? (xmax[k] + 1.f) : xmin[k];
        float u = fminf(fmaxf((float)(tile * TY + ty) + off, 0.f), 160.f);
        float uf = floorf(u);
        int i0 = (int)uf;
        sm.ru0[side][ty] = i0;
        sm.ru1[side][ty] = min(i0 + 1, 160);
        sm.rua[side][ty] = u - uf;
    }
    for (int e = tid; e < 2 * W; e += 256) {
        int side = e / W, xx = e % W;
        float off = side ? (ymax[k] + 1.f) : ymin[k];
        float v = fminf(fmaxf((float)xx + off, 0.f), 160.f);
        float vf = floorf(v);
        sm.cv0[side][xx] = (int)vf;
        sm.cva[side][xx] = v - vf;
    }
    __syncthreads();

    const float* P = II + (size_t)(b * CM + (k >> 2)) * PLANE;
    for (int e = tid; e < TY * WP; e += 256) {
        int ty = e / WP, v = e % WP;
        float al = sm.rua[0][ty], ah = sm.rua[1][ty];
        float lo = P[(size_t)sm.ru0[0][ty] * WP + v] * (1.f - al)
                 + P[(size_t)sm.ru1[0][ty] * WP + v] * al;
        float hi = P[(size_t)sm.ru0[1][ty] * WP + v] * (1.f - ah)
                 + P[(size_t)sm.ru1[1][ty] * WP + v] * ah;
        sm.D[ty][v] = hi - lo;
    }
    __syncthreads();
}

__device__ inline float eval_D(const BoxSmem& sm, int ty, int xx)
{
    int   l0 = sm.cv0[0][xx];
    float la = sm.cva[0][xx];
    int   l1 = min(l0 + 1, 160);
    int   h0 = sm.cv0[1][xx];
    float ha = sm.cva[1][xx];
    int   h1 = min(h0 + 1, 160);
    const float* Dr = sm.D[ty];
    return (Dr[h0] * (1.f - ha) + Dr[h1] * ha)
         - (Dr[l0] * (1.f - la) + Dr[l1] * la);
}

// ---------------- K4: box conv -> BN2 partial stats ----------------
__global__ __launch_bounds__(256) void k_box_part(
    const float* __restrict__ II,
    const float* __restrict__ xmin, const float* __restrict__ xmax,
    const float* __restrict__ ymin, const float* __restrict__ ymax,
    float* __restrict__ part2)
{
    __shared__ BoxSmem sm;
    __shared__ float red[4][2];
    int tile = blockIdx.x, k = blockIdx.y, b = blockIdx.z;
    fill_D(sm, II, tile, k, b, xmin, xmax, ymin, ymax);

    float s = 0.f, s2 = 0.f;
    for (int o = threadIdx.x; o < TY * W; o += 256) {
        int ty = o / W, xx = o % W;
        float v = eval_D(sm, ty, xx);
        s  += v;
        s2 += v * v;
    }
    #pragma unroll
    for (int off = 32; off > 0; off >>= 1) {
        s  += __shfl_down(s,  off);
        s2 += __shfl_down(s2, off);
    }
    int wave = threadIdx.x >> 6, lane = threadIdx.x & 63;
    if (lane == 0) { red[wave][0] = s; red[wave][1] = s2; }
    __syncthreads();
    if (threadIdx.x == 0) {
        int idx = b * NTILE + tile;     // 0..39
        part2[(size_t)k * NB2 + idx]       = red[0][0] + red[1][0] + red[2][0] + red[3][0];
        part2[(size_t)(C + k) * NB2 + idx] = red[0][1] + red[1][1] + red[2][1] + red[3][1];
    }
}

// ---------------- R2: deterministic reduction -> BN2 scale/shift ----------------
__global__ __launch_bounds__(256) void k_reduce2(
    const float* __restrict__ part2, const float* __restrict__ g2,
    const float* __restrict__ b2, float* __restrict__ sc2)
{
    __shared__ double dsum[2 * C];
    int t = threadIdx.x;                 // 256 rows, one per thread
    double acc = 0.0;
    for (int i = 0; i < NB2; ++i) acc += (double)part2[(size_t)t * NB2 + i];
    dsum[t] = acc;
    __syncthreads();
    if (t < C) {
        double n = (double)(B * HW);
        double mean = dsum[t] / n;
        double var  = dsum[C + t] / n - mean * mean;
        float inv   = (float)(1.0 / sqrt(var + 1e-5));
        float scale = g2[t] * inv;
        sc2[t]     = scale;
        sc2[C + t] = b2[t] - (float)mean * scale;
    }
}

// ---------------- K5: box conv again, BN2, relu(x + h) ----------------
__global__ __launch_bounds__(256) void k_box_final(
    const float* __restrict__ II, const float* __restrict__ x,
    const float* __restrict__ xmin, const float* __restrict__ xmax,
    const float* __restrict__ ymin, const float* __restrict__ ymax,
    const float* __restrict__ sc2, float* __restrict__ out)
{
    __shared__ BoxSmem sm;
    int tile = blockIdx.x, k = blockIdx.y, b = blockIdx.z;
    fill_D(sm, II, tile, k, b, xmin, xmax, ymin, ymax);

    float scale = sc2[k], shift = sc2[C + k];
    size_t base = ((size_t)(b * C + k)) * HW + (size_t)tile * TY * W;
    for (int o = threadIdx.x; o < TY * W; o += 256) {
        int ty = o / W, xx = o % W;
        float v = eval_D(sm, ty, xx);
        size_t idx = base + (size_t)ty * W + xx;
        out[idx] = fmaxf(x[idx] + fmaf(scale, v, shift), 0.f);
    }
}

// ---------------- launch ----------------
extern "C" void kernel_launch(void* const* d_in, const int* in_sizes, int n_in,
                              void* d_out, int out_size, void* d_ws, size_t ws_size,
                              hipStream_t stream)
{
    const float* x    = (const float*)d_in[0];
    const float* w1   = (const float*)d_in[1];
    const float* g1   = (const float*)d_in[2];
    const float* b1   = (const float*)d_in[3];
    const float* xmin = (const float*)d_in[4];
    const float* xmax = (const float*)d_in[5];
    const float* ymin = (const float*)d_in[6];
    const float* ymax = (const float*)d_in[7];
    const float* g2   = (const float*)d_in[8];
    const float* b2   = (const float*)d_in[9];
    float* out = (float*)d_out;

    // ws layout:
    //   [0,256)      sc1: BN1 scale[32] | shift[32]
    //   [256,1280)   sc2: BN2 scale[128]| shift[128]
    //   [4096, +13107200)       h   (B*CM*HW floats)
    //   [+13107200, +26379052)  II  (B*CM*PLANE floats)
    //   then qlast (B*CM*3*WP floats)
    // part1 (64*1600 floats = 409.6 KB) aliases start of II (dead before k_scan_part).
    // part2 (256*40 floats) aliases start of h (h dead after k_scan_part).
    char* ws = (char*)d_ws;
    float* sc1 = (float*)ws;
    float* sc2 = (float*)(ws + 256);
    float* h   = (float*)(ws + 4096);
    float* II  = (float*)(ws + 4096 + (size_t)B * CM * HW * sizeof(float));
    float* qlast = (float*)(ws + 4096 + (size_t)B * CM * HW * sizeof(float)
                               + (size_t)B * CM * PLANE * sizeof(float));
    float* part1 = II;
    float* part2 = h;

    k_conv     <<<dim3(K1B), 256, 0, stream>>>(x, w1, h, part1);
    k_reduce1  <<<dim3(1), 256, 0, stream>>>(part1, g1, b1, sc1);
    k_scan_part<<<dim3(B * CM * 4), 256, 0, stream>>>(h, sc1, II, qlast);
    k_scan_fix <<<dim3(B * CM * 3), 256, 0, stream>>>(II, qlast);
    k_box_part <<<dim3(NTILE, C, B), 256, 0, stream>>>(II, xmin, xmax, ymin, ymax, part2);
    k_reduce2  <<<dim3(1), 256, 0, stream>>>(part2, g2, b2, sc2);
    k_box_final<<<dim3(NTILE, C, B), 256, 0, stream>>>(II, x, xmin, xmax, ymin, ymax,
                                                       sc2, out);
}

// Round 8
// 148.250 us; speedup vs baseline: 1.1142x; 1.1142x over previous
//
#include <hip/hip_runtime.h>
#include <cstdint>

constexpr int B  = 4;
constexpr int C  = 128;
constexpr int CM = 32;        // mid channels
constexpr int H  = 160;
constexpr int W  = 160;
constexpr int HW = H * W;     // 25600
constexpr int HP = H + 1;     // 161
constexpr int WP = W + 1;     // 161
constexpr int PLANE = HP * WP; // 25921
constexpr int TY = 16;         // rows per box tile
constexpr int NTILE = H / TY;  // 10
constexpr int PB  = 64;        // positions per conv block
constexpr int K1B = B * HW / PB; // 1600 conv blocks
constexpr int NB2 = B * NTILE; // 40 partials per out-channel
constexpr int QR = 40;         // rows per scan quarter

// ---------------- K0: transpose w1 [CM][C] -> wTg [C][CM] (16 KB, once) ----------------
__global__ __launch_bounds__(256) void k_transpose_w(
    const float* __restrict__ w1, float* __restrict__ wTg)
{
    int t = blockIdx.x * 256 + threadIdx.x;    // 4096 elements
    if (t < C * CM) {
        int o = t / C, c = t % C;
        wTg[c * CM + o] = w1[t];
    }
}

// ------- K1: 1x1 conv, split-C: wave q owns c in [32q,32q+32), 64 pos/block -------
//         weights via scalar (s_load) reads from wTg; partials reduced in LDS
__global__ __launch_bounds__(256) void k_conv(
    const float* __restrict__ x, const float* __restrict__ wTg,
    float* __restrict__ h, float* __restrict__ part1)
{
    __shared__ float part[4 * CM * PB];   // 32 KB: [q][o][lane]
    int tid = threadIdx.x;
    int wave = tid >> 6, lane = tid & 63;
    int bid = blockIdx.x;                 // 1600 blocks; 400 per batch image
    int b = bid / 400;
    int p0 = (bid % 400) * PB;

    int wq = __builtin_amdgcn_readfirstlane(wave);   // uniform wave id -> SGPR
    const float* xb = x + (size_t)b * C * HW + (size_t)(wq * 32) * HW + p0 + lane;
    const float* wrow = wTg + (size_t)(wq * 32) * CM;  // uniform base -> s_loads

    float acc[CM];
    #pragma unroll
    for (int o = 0; o < CM; ++o) acc[o] = 0.f;

    #pragma unroll 4
    for (int i = 0; i < 32; ++i) {
        float xv = xb[(size_t)i * HW];               // coalesced 256B vector load
        const float* wr = wrow + i * CM;             // uniform -> scalar loads
        #pragma unroll
        for (int o = 0; o < CM; ++o)
            acc[o] = fmaf(wr[o], xv, acc[o]);        // SGPR-operand FMA
    }

    // dump partials: per o, 64 consecutive floats -> conflict-free
    float* pq = &part[wave * CM * PB];
    #pragma unroll
    for (int o = 0; o < CM; ++o) pq[o * PB + lane] = acc[o];
    __syncthreads();

    // final: thread t owns 8 consecutive finals (one o, lanes l0..l0+7)
    int o  = tid >> 3;                 // 0..31
    int l0 = (tid & 7) * 8;
    const float* pp = &part[o * PB + l0];
    float4 f0 = *reinterpret_cast<const float4*>(pp);
    float4 f1 = *reinterpret_cast<const float4*>(pp + 4);
    #pragma unroll
    for (int q = 1; q < 4; ++q) {
        const float4 a0 = *reinterpret_cast<const float4*>(pp + q * CM * PB);
        const float4 a1 = *reinterpret_cast<const float4*>(pp + q * CM * PB + 4);
        f0.x += a0.x; f0.y += a0.y; f0.z += a0.z; f0.w += a0.w;
        f1.x += a1.x; f1.y += a1.y; f1.z += a1.z; f1.w += a1.w;
    }

    float* hb = h + ((size_t)(b * CM + o)) * HW + p0 + l0;
    *reinterpret_cast<float4*>(hb)     = f0;
    *reinterpret_cast<float4*>(hb + 4) = f1;

    // stats: sum / sumsq over this thread's 8, then over the 8 threads sharing o
    float s  = f0.x + f0.y + f0.z + f0.w + f1.x + f1.y + f1.z + f1.w;
    float s2 = f0.x * f0.x + f0.y * f0.y + f0.z * f0.z + f0.w * f0.w
             + f1.x * f1.x + f1.y * f1.y + f1.z * f1.z + f1.w * f1.w;
    #pragma unroll
    for (int off = 4; off > 0; off >>= 1) {
        s  += __shfl_down(s,  off, 8);
        s2 += __shfl_down(s2, off, 8);
    }
    if ((tid & 7) == 0) {
        part1[(size_t)o * K1B + bid]        = s;   // row o      : sums
        part1[(size_t)(o + CM) * K1B + bid] = s2;  // row CM + o : sumsq
    }
}

// ---------------- R1: deterministic reduction -> BN1 scale/shift ----------------
__global__ __launch_bounds__(256) void k_reduce1(
    const float* __restrict__ part1, const float* __restrict__ g1,
    const float* __restrict__ b1, float* __restrict__ sc1)
{
    __shared__ double pr[256];
    __shared__ double dsum[2 * CM];
    int t = threadIdx.x;
    int row = t >> 2, j = t & 3;        // 64 rows x 4 threads
    double acc = 0.0;
    for (int i = j; i < K1B; i += 4) acc += (double)part1[(size_t)row * K1B + i];
    pr[t] = acc;
    __syncthreads();
    if (j == 0) dsum[row] = pr[t] + pr[t + 1] + pr[t + 2] + pr[t + 3];
    __syncthreads();
    if (t < CM) {
        double n = (double)(B * HW);
        double mean = dsum[t] / n;
        double var  = dsum[CM + t] / n - mean * mean;
        float inv   = (float)(1.0 / sqrt(var + 1e-5));
        float scale = g1[t] * inv;
        sc1[t]      = scale;
        sc1[CM + t] = b1[t] - (float)mean * scale;
    }
}

// ------- K2a: BN1+ReLU + row scan + LOCAL col scan per (plane, quarter) -------
//         also emits pre-fix local last row to qlast[plane][q] for q < 3
__global__ __launch_bounds__(256) void k_scan_part(
    const float* __restrict__ h, const float* __restrict__ sc1,
    float* __restrict__ II, float* __restrict__ qlast)
{
    __shared__ float buf[QR * W];   // 40 row-scanned rows, 25600 B
    int tid = threadIdx.x;
    int wave = tid >> 6, lane = tid & 63;
    int blk = blockIdx.x;           // plane*4 + q
    int plane = blk >> 2, q = blk & 3;
    int cm = plane & (CM - 1);

    float scale = sc1[cm];
    float shift = sc1[CM + cm];

    const float* hp = h + (size_t)plane * HW + (size_t)q * QR * W;
    float* IIp = II + (size_t)plane * PLANE;

    // top border row (quarter 0 only) — independent of buf
    if (q == 0) {
        for (int e = tid; e < WP; e += 256) IIp[e] = 0.f;
    }

    // phase 1: BN+ReLU + row inclusive scan into LDS (wave-per-row shuffle scan)
    for (int y = wave; y < QR; y += 4) {
        const float* hr = hp + (size_t)y * W;
        float carry = 0.f;
        #pragma unroll
        for (int x0 = 0; x0 < W; x0 += 64) {
            int xx = x0 + lane;
            float v = (xx < W) ? fmaxf(fmaf(scale, hr[xx], shift), 0.f) : 0.f;
            #pragma unroll
            for (int off = 1; off < 64; off <<= 1) {
                float t = __shfl_up(v, off);
                if (lane >= off) v += t;
            }
            v += carry;
            if (xx < W) buf[y * W + xx] = v;
            carry = __shfl(v, 63);
        }
    }
    __syncthreads();

    // phase 2: local column scan + write II rows q*40+1 .. q*40+40
    float* op = IIp + (size_t)(q * QR + 1) * WP;
    float* ql = qlast + ((size_t)plane * 3 + q) * WP;
    if (tid <= W) {
        float run = 0.f;
        #pragma unroll 4
        for (int r = 0; r < QR; ++r) {
            float v = 0.f;
            if (tid > 0) { run += buf[r * W + (tid - 1)]; v = run; }
            op[(size_t)r * WP + tid] = v;
            if (r == QR - 1 && q < 3) ql[tid] = v;
        }
    }
}

// ------- K2b: add cross-quarter offsets; block = (plane, chunk f of rows 41+40f..80+40f) -------
__global__ __launch_bounds__(256) void k_scan_fix(
    float* __restrict__ II, const float* __restrict__ qlast)
{
    __shared__ float off[WP];
    int tid = threadIdx.x;
    int blk = blockIdx.x;
    int plane = blk / 3, f = blk % 3;

    const float* qb = qlast + (size_t)plane * 3 * WP;
    for (int v = tid; v < WP; v += 256) {
        float s = qb[v];
        if (f >= 1) s += qb[WP + v];
        if (f >= 2) s += qb[2 * WP + v];
        off[v] = s;
    }
    __syncthreads();

    float* P = II + (size_t)plane * PLANE + (size_t)(41 + f * QR) * WP;
    constexpr int total = QR * WP;
    for (int e = tid; e < total; e += 256) {
        P[e] += off[e % WP];
    }
}

// ---------------- box tile machinery ----------------
struct BoxSmem {
    float D[TY][WP];      // row-interp difference rows
    int   ru0[2][TY];     // [0]=lo, [1]=hi row coords
    int   ru1[2][TY];
    float rua[2][TY];
    int   cv0[2][W];      // col coords ([0]=lo, [1]=hi)
    float cva[2][W];
};

__device__ inline void fill_D(BoxSmem& sm, const float* __restrict__ II,
    int tile, int k, int b,
    const float* __restrict__ xmin, const float* __restrict__ xmax,
    const float* __restrict__ ymin, const float* __restrict__ ymax)
{
    int tid = threadIdx.x;
    if (tid < 2 * TY) {
        int side = tid / TY, ty = tid % TY;
        float off = side ? (xmax[k] + 1.f) : xmin[k];
        float u = fminf(fmaxf((float)(tile * TY + ty) + off, 0.f), 160.f);
        float uf = floorf(u);
        int i0 = (int)uf;
        sm.ru0[side][ty] = i0;
        sm.ru1[side][ty] = min(i0 + 1, 160);
        sm.rua[side][ty] = u - uf;
    }
    for (int e = tid; e < 2 * W; e += 256) {
        int side = e / W, xx = e % W;
        float off = side ? (ymax[k] + 1.f) : ymin[k];
        float v = fminf(fmaxf((float)xx + off, 0.f), 160.f);
        float vf = floorf(v);
        sm.cv0[side][xx] = (int)vf;
        sm.cva[side][xx] = v - vf;
    }
    __syncthreads();

    const float* P = II + (size_t)(b * CM + (k >> 2)) * PLANE;
    for (int e = tid; e < TY * WP; e += 256) {
        int ty = e / WP, v = e % WP;
        float al = sm.rua[0][ty], ah = sm.rua[1][ty];
        float lo = P[(size_t)sm.ru0[0][ty] * WP + v] * (1.f - al)
                 + P[(size_t)sm.ru1[0][ty] * WP + v] * al;
        float hi = P[(size_t)sm.ru0[1][ty] * WP + v] * (1.f - ah)
                 + P[(size_t)sm.ru1[1][ty] * WP + v] * ah;
        sm.D[ty][v] = hi - lo;
    }
    __syncthreads();
}

__device__ inline float eval_D(const BoxSmem& sm, int ty, int xx)
{
    int   l0 = sm.cv0[0][xx];
    float la = sm.cva[0][xx];
    int   l1 = min(l0 + 1, 160);
    int   h0 = sm.cv0[1][xx];
    float ha = sm.cva[1][xx];
    int   h1 = min(h0 + 1, 160);
    const float* Dr = sm.D[ty];
    return (Dr[h0] * (1.f - ha) + Dr[h1] * ha)
         - (Dr[l0] * (1.f - la) + Dr[l1] * la);
}

// ---------------- K4: box conv -> BN2 partial stats ----------------
__global__ __launch_bounds__(256) void k_box_part(
    const float* __restrict__ II,
    const float* __restrict__ xmin, const float* __restrict__ xmax,
    const float* __restrict__ ymin, const float* __restrict__ ymax,
    float* __restrict__ part2)
{
    __shared__ BoxSmem sm;
    __shared__ float red[4][2];
    int tile = blockIdx.x, k = blockIdx.y, b = blockIdx.z;
    fill_D(sm, II, tile, k, b, xmin, xmax, ymin, ymax);

    float s = 0.f, s2 = 0.f;
    for (int o = threadIdx.x; o < TY * W; o += 256) {
        int ty = o / W, xx = o % W;
        float v = eval_D(sm, ty, xx);
        s  += v;
        s2 += v * v;
    }
    #pragma unroll
    for (int off = 32; off > 0; off >>= 1) {
        s  += __shfl_down(s,  off);
        s2 += __shfl_down(s2, off);
    }
    int wave = threadIdx.x >> 6, lane = threadIdx.x & 63;
    if (lane == 0) { red[wave][0] = s; red[wave][1] = s2; }
    __syncthreads();
    if (threadIdx.x == 0) {
        int idx = b * NTILE + tile;     // 0..39
        part2[(size_t)k * NB2 + idx]       = red[0][0] + red[1][0] + red[2][0] + red[3][0];
        part2[(size_t)(C + k) * NB2 + idx] = red[0][1] + red[1][1] + red[2][1] + red[3][1];
    }
}

// ---------------- R2: deterministic reduction -> BN2 scale/shift ----------------
__global__ __launch_bounds__(256) void k_reduce2(
    const float* __restrict__ part2, const float* __restrict__ g2,
    const float* __restrict__ b2, float* __restrict__ sc2)
{
    __shared__ double dsum[2 * C];
    int t = threadIdx.x;                 // 256 rows, one per thread
    double acc = 0.0;
    for (int i = 0; i < NB2; ++i) acc += (double)part2[(size_t)t * NB2 + i];
    dsum[t] = acc;
    __syncthreads();
    if (t < C) {
        double n = (double)(B * HW);
        double mean = dsum[t] / n;
        double var  = dsum[C + t] / n - mean * mean;
        float inv   = (float)(1.0 / sqrt(var + 1e-5));
        float scale = g2[t] * inv;
        sc2[t]     = scale;
        sc2[C + t] = b2[t] - (float)mean * scale;
    }
}

// ---------------- K5: box conv again, BN2, relu(x + h) ----------------
__global__ __launch_bounds__(256) void k_box_final(
    const float* __restrict__ II, const float* __restrict__ x,
    const float* __restrict__ xmin, const float* __restrict__ xmax,
    const float* __restrict__ ymin, const float* __restrict__ ymax,
    const float* __restrict__ sc2, float* __restrict__ out)
{
    __shared__ BoxSmem sm;
    int tile = blockIdx.x, k = blockIdx.y, b = blockIdx.z;
    fill_D(sm, II, tile, k, b, xmin, xmax, ymin, ymax);

    float scale = sc2[k], shift = sc2[C + k];
    size_t base = ((size_t)(b * C + k)) * HW + (size_t)tile * TY * W;
    for (int o = threadIdx.x; o < TY * W; o += 256) {
        int ty = o / W, xx = o % W;
        float v = eval_D(sm, ty, xx);
        size_t idx = base + (size_t)ty * W + xx;
        out[idx] = fmaxf(x[idx] + fmaf(scale, v, shift), 0.f);
    }
}

// ---------------- launch ----------------
extern "C" void kernel_launch(void* const* d_in, const int* in_sizes, int n_in,
                              void* d_out, int out_size, void* d_ws, size_t ws_size,
                              hipStream_t stream)
{
    const float* x    = (const float*)d_in[0];
    const float* w1   = (const float*)d_in[1];
    const float* g1   = (const float*)d_in[2];
    const float* b1   = (const float*)d_in[3];
    const float* xmin = (const float*)d_in[4];
    const float* xmax = (const float*)d_in[5];
    const float* ymin = (const float*)d_in[6];
    const float* ymax = (const float*)d_in[7];
    const float* g2   = (const float*)d_in[8];
    const float* b2   = (const float*)d_in[9];
    float* out = (float*)d_out;

    // ws layout:
    //   [0,256)       sc1: BN1 scale[32] | shift[32]
    //   [256,1280)    sc2: BN2 scale[128]| shift[128]
    //   [1280, +16K)  wTg (C*CM floats, transposed weights)
    //   [20480, +13107200)      h   (B*CM*HW floats)
    //   [+13107200, +26379052)  II  (B*CM*PLANE floats)
    //   then qlast (B*CM*3*WP floats)
    // part1 (64*1600 floats) aliases start of II (dead before k_scan_part).
    // part2 (256*40 floats) aliases start of h (h dead after k_scan_part).
    char* ws = (char*)d_ws;
    float* sc1 = (float*)ws;
    float* sc2 = (float*)(ws + 256);
    float* wTg = (float*)(ws + 1280);
    float* h   = (float*)(ws + 20480);
    float* II  = (float*)(ws + 20480 + (size_t)B * CM * HW * sizeof(float));
    float* qlast = (float*)(ws + 20480 + (size_t)B * CM * HW * sizeof(float)
                               + (size_t)B * CM * PLANE * sizeof(float));
    float* part1 = II;
    float* part2 = h;

    k_transpose_w<<<dim3((C * CM + 255) / 256), 256, 0, stream>>>(w1, wTg);
    k_conv     <<<dim3(K1B), 256, 0, stream>>>(x, wTg, h, part1);
    k_reduce1  <<<dim3(1), 256, 0, stream>>>(part1, g1, b1, sc1);
    k_scan_part<<<dim3(B * CM * 4), 256, 0, stream>>>(h, sc1, II, qlast);
    k_scan_fix <<<dim3(B * CM * 3), 256, 0, stream>>>(II, qlast);
    k_box_part <<<dim3(NTILE, C, B), 256, 0, stream>>>(II, xmin, xmax, ymin, ymax, part2);
    k_reduce2  <<<dim3(1), 256, 0, stream>>>(part2, g2, b2, sc2);
    k_box_final<<<dim3(NTILE, C, B), 256, 0, stream>>>(II, x, xmin, xmax, ymin, ymax,
                                                       sc2, out);
}

// Round 9
// 111.766 us; speedup vs baseline: 1.4779x; 1.3264x over previous
//
#include <hip/hip_runtime.h>
#include <cstdint>

constexpr int B  = 4;
constexpr int C  = 128;
constexpr int CM = 32;        // mid channels
constexpr int H  = 160;
constexpr int W  = 160;
constexpr int HW = H * W;     // 25600
constexpr int HP = H + 1;     // 161
constexpr int WP = W + 1;     // 161
constexpr int PLANE = HP * WP; // 25921
constexpr int TY = 16;         // rows per box tile
constexpr int NTILE = H / TY;  // 10
constexpr int PB  = 64;        // positions per conv block
constexpr int K1B = B * HW / PB; // 1600 conv blocks
constexpr int NB2 = B * NTILE; // 40 partials per out-channel
constexpr int QR = 40;         // rows per scan quarter

// ---------------- K0: transpose w1 [CM][C] -> wTg [C][CM] (16 KB, once) ----------------
__global__ __launch_bounds__(256) void k_transpose_w(
    const float* __restrict__ w1, float* __restrict__ wTg)
{
    int t = blockIdx.x * 256 + threadIdx.x;    // 4096 elements
    if (t < C * CM) {
        int o = t / C, c = t % C;
        wTg[c * CM + o] = w1[t];
    }
}

// ------- K1: 1x1 conv, split-C: wave q owns c in [32q,32q+32), 64 pos/block -------
//         weights via scalar (s_load) reads from wTg; partials reduced in LDS
__global__ __launch_bounds__(256) void k_conv(
    const float* __restrict__ x, const float* __restrict__ wTg,
    float* __restrict__ h, float* __restrict__ part1)
{
    __shared__ float part[4 * CM * PB];   // 32 KB: [q][o][lane]
    int tid = threadIdx.x;
    int wave = tid >> 6, lane = tid & 63;
    int bid = blockIdx.x;                 // 1600 blocks; 400 per batch image
    int b = bid / 400;
    int p0 = (bid % 400) * PB;

    int wq = __builtin_amdgcn_readfirstlane(wave);   // uniform wave id -> SGPR
    const float* xb = x + (size_t)b * C * HW + (size_t)(wq * 32) * HW + p0 + lane;
    const float* wrow = wTg + (size_t)(wq * 32) * CM;  // uniform base -> s_loads

    float acc[CM];
    #pragma unroll
    for (int o = 0; o < CM; ++o) acc[o] = 0.f;

    #pragma unroll 4
    for (int i = 0; i < 32; ++i) {
        float xv = xb[(size_t)i * HW];               // coalesced 256B vector load
        const float* wr = wrow + i * CM;             // uniform -> scalar loads
        #pragma unroll
        for (int o = 0; o < CM; ++o)
            acc[o] = fmaf(wr[o], xv, acc[o]);        // SGPR-operand FMA
    }

    // dump partials: per o, 64 consecutive floats -> conflict-free
    float* pq = &part[wave * CM * PB];
    #pragma unroll
    for (int o = 0; o < CM; ++o) pq[o * PB + lane] = acc[o];
    __syncthreads();

    // final: thread t owns 8 consecutive finals (one o, lanes l0..l0+7)
    int o  = tid >> 3;                 // 0..31
    int l0 = (tid & 7) * 8;
    const float* pp = &part[o * PB + l0];
    float4 f0 = *reinterpret_cast<const float4*>(pp);
    float4 f1 = *reinterpret_cast<const float4*>(pp + 4);
    #pragma unroll
    for (int q = 1; q < 4; ++q) {
        const float4 a0 = *reinterpret_cast<const float4*>(pp + q * CM * PB);
        const float4 a1 = *reinterpret_cast<const float4*>(pp + q * CM * PB + 4);
        f0.x += a0.x; f0.y += a0.y; f0.z += a0.z; f0.w += a0.w;
        f1.x += a1.x; f1.y += a1.y; f1.z += a1.z; f1.w += a1.w;
    }

    float* hb = h + ((size_t)(b * CM + o)) * HW + p0 + l0;
    *reinterpret_cast<float4*>(hb)     = f0;
    *reinterpret_cast<float4*>(hb + 4) = f1;

    // stats: sum / sumsq over this thread's 8, then over the 8 threads sharing o
    float s  = f0.x + f0.y + f0.z + f0.w + f1.x + f1.y + f1.z + f1.w;
    float s2 = f0.x * f0.x + f0.y * f0.y + f0.z * f0.z + f0.w * f0.w
             + f1.x * f1.x + f1.y * f1.y + f1.z * f1.z + f1.w * f1.w;
    #pragma unroll
    for (int off = 4; off > 0; off >>= 1) {
        s  += __shfl_down(s,  off, 8);
        s2 += __shfl_down(s2, off, 8);
    }
    if ((tid & 7) == 0) {
        part1[(size_t)o * K1B + bid]        = s;   // row o      : sums
        part1[(size_t)(o + CM) * K1B + bid] = s2;  // row CM + o : sumsq
    }
}

// ---------------- R1: parallel row-sums (64 blocks, coalesced) ----------------
__global__ __launch_bounds__(256) void k_rowsum1(
    const float* __restrict__ part1, double* __restrict__ rowsum1)
{
    __shared__ double red[256];
    int tid = threadIdx.x;
    int r = blockIdx.x;                      // 0..63
    const float* row = part1 + (size_t)r * K1B;
    double a = 0.0;
    for (int i = tid; i < K1B; i += 256) a += (double)row[i];
    red[tid] = a;
    __syncthreads();
    #pragma unroll
    for (int s = 128; s > 0; s >>= 1) {
        if (tid < s) red[tid] += red[tid + s];
        __syncthreads();
    }
    if (tid == 0) rowsum1[r] = red[0];
}

// ------- K2a: BN1 (from rowsum1) + ReLU + row scan + LOCAL col scan per (plane, quarter) -------
//         also emits pre-fix local last row to qlast[plane][q] for q < 3
__global__ __launch_bounds__(256) void k_scan_part(
    const float* __restrict__ h, const double* __restrict__ rowsum1,
    const float* __restrict__ g1, const float* __restrict__ b1,
    float* __restrict__ II, float* __restrict__ qlast)
{
    __shared__ float buf[QR * W];   // 40 row-scanned rows, 25600 B
    int tid = threadIdx.x;
    int wave = tid >> 6, lane = tid & 63;
    int blk = blockIdx.x;           // plane*4 + q
    int plane = blk >> 2, q = blk & 3;
    int cm = plane & (CM - 1);

    double n = (double)(B * HW);
    double mean = rowsum1[cm] / n;
    double var  = rowsum1[CM + cm] / n - mean * mean;
    float inv   = (float)(1.0 / sqrt(var + 1e-5));
    float scale = g1[cm] * inv;
    float shift = b1[cm] - (float)mean * scale;

    const float* hp = h + (size_t)plane * HW + (size_t)q * QR * W;
    float* IIp = II + (size_t)plane * PLANE;

    // top border row (quarter 0 only) — independent of buf
    if (q == 0) {
        for (int e = tid; e < WP; e += 256) IIp[e] = 0.f;
    }

    // phase 1: BN+ReLU + row inclusive scan into LDS (wave-per-row shuffle scan)
    for (int y = wave; y < QR; y += 4) {
        const float* hr = hp + (size_t)y * W;
        float carry = 0.f;
        #pragma unroll
        for (int x0 = 0; x0 < W; x0 += 64) {
            int xx = x0 + lane;
            float v = (xx < W) ? fmaxf(fmaf(scale, hr[xx], shift), 0.f) : 0.f;
            #pragma unroll
            for (int off = 1; off < 64; off <<= 1) {
                float t = __shfl_up(v, off);
                if (lane >= off) v += t;
            }
            v += carry;
            if (xx < W) buf[y * W + xx] = v;
            carry = __shfl(v, 63);
        }
    }
    __syncthreads();

    // phase 2: local column scan + write II rows q*40+1 .. q*40+40
    float* op = IIp + (size_t)(q * QR + 1) * WP;
    float* ql = qlast + ((size_t)plane * 3 + q) * WP;
    if (tid <= W) {
        float run = 0.f;
        #pragma unroll 4
        for (int r = 0; r < QR; ++r) {
            float v = 0.f;
            if (tid > 0) { run += buf[r * W + (tid - 1)]; v = run; }
            op[(size_t)r * WP + tid] = v;
            if (r == QR - 1 && q < 3) ql[tid] = v;
        }
    }
}

// ------- K2b: add cross-quarter offsets; block = (plane, chunk f of rows 41+40f..80+40f) -------
__global__ __launch_bounds__(256) void k_scan_fix(
    float* __restrict__ II, const float* __restrict__ qlast)
{
    __shared__ float off[WP];
    int tid = threadIdx.x;
    int blk = blockIdx.x;
    int plane = blk / 3, f = blk % 3;

    const float* qb = qlast + (size_t)plane * 3 * WP;
    for (int v = tid; v < WP; v += 256) {
        float s = qb[v];
        if (f >= 1) s += qb[WP + v];
        if (f >= 2) s += qb[2 * WP + v];
        off[v] = s;
    }
    __syncthreads();

    float* P = II + (size_t)plane * PLANE + (size_t)(41 + f * QR) * WP;
    constexpr int total = QR * WP;
    for (int e = tid; e < total; e += 256) {
        P[e] += off[e % WP];
    }
}

// ---------------- box tile machinery ----------------
struct BoxSmem {
    float D[TY][WP];      // row-interp difference rows
    int   ru0[2][TY];     // [0]=lo, [1]=hi row coords
    int   ru1[2][TY];
    float rua[2][TY];
    int   cv0[2][W];      // col coords ([0]=lo, [1]=hi)
    float cva[2][W];
};

__device__ inline void fill_D(BoxSmem& sm, const float* __restrict__ II,
    int tile, int k, int b,
    const float* __restrict__ xmin, const float* __restrict__ xmax,
    const float* __restrict__ ymin, const float* __restrict__ ymax)
{
    int tid = threadIdx.x;
    if (tid < 2 * TY) {
        int side = tid / TY, ty = tid % TY;
        float off = side ? (xmax[k] + 1.f) : xmin[k];
        float u = fminf(fmaxf((float)(tile * TY + ty) + off, 0.f), 160.f);
        float uf = floorf(u);
        int i0 = (int)uf;
        sm.ru0[side][ty] = i0;
        sm.ru1[side][ty] = min(i0 + 1, 160);
        sm.rua[side][ty] = u - uf;
    }
    for (int e = tid; e < 2 * W; e += 256) {
        int side = e / W, xx = e % W;
        float off = side ? (ymax[k] + 1.f) : ymin[k];
        float v = fminf(fmaxf((float)xx + off, 0.f), 160.f);
        float vf = floorf(v);
        sm.cv0[side][xx] = (int)vf;
        sm.cva[side][xx] = v - vf;
    }
    __syncthreads();

    const float* P = II + (size_t)(b * CM + (k >> 2)) * PLANE;
    for (int e = tid; e < TY * WP; e += 256) {
        int ty = e / WP, v = e % WP;
        float al = sm.rua[0][ty], ah = sm.rua[1][ty];
        float lo = P[(size_t)sm.ru0[0][ty] * WP + v] * (1.f - al)
                 + P[(size_t)sm.ru1[0][ty] * WP + v] * al;
        float hi = P[(size_t)sm.ru0[1][ty] * WP + v] * (1.f - ah)
                 + P[(size_t)sm.ru1[1][ty] * WP + v] * ah;
        sm.D[ty][v] = hi - lo;
    }
    __syncthreads();
}

__device__ inline float eval_D(const BoxSmem& sm, int ty, int xx)
{
    int   l0 = sm.cv0[0][xx];
    float la = sm.cva[0][xx];
    int   l1 = min(l0 + 1, 160);
    int   h0 = sm.cv0[1][xx];
    float ha = sm.cva[1][xx];
    int   h1 = min(h0 + 1, 160);
    const float* Dr = sm.D[ty];
    return (Dr[h0] * (1.f - ha) + Dr[h1] * ha)
         - (Dr[l0] * (1.f - la) + Dr[l1] * la);
}

// ---------------- K4: box conv -> BN2 partial stats ----------------
__global__ __launch_bounds__(256) void k_box_part(
    const float* __restrict__ II,
    const float* __restrict__ xmin, const float* __restrict__ xmax,
    const float* __restrict__ ymin, const float* __restrict__ ymax,
    float* __restrict__ part2)
{
    __shared__ BoxSmem sm;
    __shared__ float red[4][2];
    int tile = blockIdx.x, k = blockIdx.y, b = blockIdx.z;
    fill_D(sm, II, tile, k, b, xmin, xmax, ymin, ymax);

    float s = 0.f, s2 = 0.f;
    for (int o = threadIdx.x; o < TY * W; o += 256) {
        int ty = o / W, xx = o % W;
        float v = eval_D(sm, ty, xx);
        s  += v;
        s2 += v * v;
    }
    #pragma unroll
    for (int off = 32; off > 0; off >>= 1) {
        s  += __shfl_down(s,  off);
        s2 += __shfl_down(s2, off);
    }
    int wave = threadIdx.x >> 6, lane = threadIdx.x & 63;
    if (lane == 0) { red[wave][0] = s; red[wave][1] = s2; }
    __syncthreads();
    if (threadIdx.x == 0) {
        int idx = b * NTILE + tile;     // 0..39
        part2[(size_t)k * NB2 + idx]       = red[0][0] + red[1][0] + red[2][0] + red[3][0];
        part2[(size_t)(C + k) * NB2 + idx] = red[0][1] + red[1][1] + red[2][1] + red[3][1];
    }
}

// ---------------- R2: deterministic reduction -> BN2 scale/shift ----------------
__global__ __launch_bounds__(256) void k_reduce2(
    const float* __restrict__ part2, const float* __restrict__ g2,
    const float* __restrict__ b2, float* __restrict__ sc2)
{
    __shared__ double dsum[2 * C];
    int t = threadIdx.x;                 // 256 rows, one per thread
    const float4* rp = reinterpret_cast<const float4*>(part2 + (size_t)t * NB2);
    double acc = 0.0;
    #pragma unroll
    for (int i = 0; i < NB2 / 4; ++i) {
        float4 v = rp[i];
        acc += (double)v.x + (double)v.y + (double)v.z + (double)v.w;
    }
    dsum[t] = acc;
    __syncthreads();
    if (t < C) {
        double n = (double)(B * HW);
        double mean = dsum[t] / n;
        double var  = dsum[C + t] / n - mean * mean;
        float inv   = (float)(1.0 / sqrt(var + 1e-5));
        float scale = g2[t] * inv;
        sc2[t]     = scale;
        sc2[C + t] = b2[t] - (float)mean * scale;
    }
}

// ---------------- K5: box conv again, BN2, relu(x + h) ----------------
__global__ __launch_bounds__(256) void k_box_final(
    const float* __restrict__ II, const float* __restrict__ x,
    const float* __restrict__ xmin, const float* __restrict__ xmax,
    const float* __restrict__ ymin, const float* __restrict__ ymax,
    const float* __restrict__ sc2, float* __restrict__ out)
{
    __shared__ BoxSmem sm;
    int tile = blockIdx.x, k = blockIdx.y, b = blockIdx.z;
    fill_D(sm, II, tile, k, b, xmin, xmax, ymin, ymax);

    float scale = sc2[k], shift = sc2[C + k];
    size_t base = ((size_t)(b * C + k)) * HW + (size_t)tile * TY * W;
    for (int o = threadIdx.x; o < TY * W; o += 256) {
        int ty = o / W, xx = o % W;
        float v = eval_D(sm, ty, xx);
        size_t idx = base + (size_t)ty * W + xx;
        out[idx] = fmaxf(x[idx] + fmaf(scale, v, shift), 0.f);
    }
}

// ---------------- launch ----------------
extern "C" void kernel_launch(void* const* d_in, const int* in_sizes, int n_in,
                              void* d_out, int out_size, void* d_ws, size_t ws_size,
                              hipStream_t stream)
{
    const float* x    = (const float*)d_in[0];
    const float* w1   = (const float*)d_in[1];
    const float* g1   = (const float*)d_in[2];
    const float* b1   = (const float*)d_in[3];
    const float* xmin = (const float*)d_in[4];
    const float* xmax = (const float*)d_in[5];
    const float* ymin = (const float*)d_in[6];
    const float* ymax = (const float*)d_in[7];
    const float* g2   = (const float*)d_in[8];
    const float* b2   = (const float*)d_in[9];
    float* out = (float*)d_out;

    // ws layout:
    //   [0,1024)      sc2: BN2 scale[128]| shift[128]
    //   [1280, +16K)  wTg (C*CM floats, transposed weights)
    //   [17664, +512) rowsum1 (64 doubles)
    //   [20480, +13107200)      h   (B*CM*HW floats)
    //   [+13107200, +26379052)  II  (B*CM*PLANE floats)
    //   then qlast (B*CM*3*WP floats)
    // part1 (64*1600 floats) aliases start of II (dead before k_scan_part).
    // part2 (256*40 floats) aliases start of h (h dead after k_scan_part).
    char* ws = (char*)d_ws;
    float* sc2 = (float*)ws;
    float* wTg = (float*)(ws + 1280);
    double* rowsum1 = (double*)(ws + 17664);
    float* h   = (float*)(ws + 20480);
    float* II  = (float*)(ws + 20480 + (size_t)B * CM * HW * sizeof(float));
    float* qlast = (float*)(ws + 20480 + (size_t)B * CM * HW * sizeof(float)
                               + (size_t)B * CM * PLANE * sizeof(float));
    float* part1 = II;
    float* part2 = h;

    k_transpose_w<<<dim3((C * CM + 255) / 256), 256, 0, stream>>>(w1, wTg);
    k_conv     <<<dim3(K1B), 256, 0, stream>>>(x, wTg, h, part1);
    k_rowsum1  <<<dim3(2 * CM), 256, 0, stream>>>(part1, rowsum1);
    k_scan_part<<<dim3(B * CM * 4), 256, 0, stream>>>(h, rowsum1, g1, b1, II, qlast);
    k_scan_fix <<<dim3(B * CM * 3), 256, 0, stream>>>(II, qlast);
    k_box_part <<<dim3(NTILE, C, B), 256, 0, stream>>>(II, xmin, xmax, ymin, ymax, part2);
    k_reduce2  <<<dim3(1), 256, 0, stream>>>(part2, g2, b2, sc2);
    k_box_final<<<dim3(NTILE, C, B), 256, 0, stream>>>(II, x, xmin, xmax, ymin, ymax,
                                                       sc2, out);
}

// Round 10
// 103.148 us; speedup vs baseline: 1.6014x; 1.0835x over previous
//
#include <hip/hip_runtime.h>
#include <cstdint>

constexpr int B  = 4;
constexpr int C  = 128;
constexpr int CM = 32;        // mid channels
constexpr int H  = 160;
constexpr int W  = 160;
constexpr int HW = H * W;     // 25600
constexpr int HP = H + 1;     // 161
constexpr int WP = W + 1;     // 161
constexpr int PLANE = HP * WP; // 25921
constexpr int TY = 16;         // rows per box tile
constexpr int NTILE = H / TY;  // 10
constexpr int PB  = 64;        // positions per conv block
constexpr int K1B = B * HW / PB; // 1600 conv blocks
constexpr int NB2 = B * NTILE; // 40 partials per out-channel
constexpr int QR = 40;         // rows per scan quarter

// ---------------- K0: transpose w1 [CM][C] -> wTg [C][CM] (16 KB, once) ----------------
__global__ __launch_bounds__(256) void k_transpose_w(
    const float* __restrict__ w1, float* __restrict__ wTg)
{
    int t = blockIdx.x * 256 + threadIdx.x;    // 4096 elements
    if (t < C * CM) {
        int o = t / C, c = t % C;
        wTg[c * CM + o] = w1[t];
    }
}

// ------- K1: 1x1 conv, split-C: wave q owns c in [32q,32q+32), 64 pos/block -------
//         weights via scalar (s_load) reads from wTg; partials reduced in LDS
__global__ __launch_bounds__(256) void k_conv(
    const float* __restrict__ x, const float* __restrict__ wTg,
    float* __restrict__ h, float* __restrict__ part1)
{
    __shared__ float part[4 * CM * PB];   // 32 KB: [q][o][lane]
    int tid = threadIdx.x;
    int wave = tid >> 6, lane = tid & 63;
    int bid = blockIdx.x;                 // 1600 blocks; 400 per batch image
    int b = bid / 400;
    int p0 = (bid % 400) * PB;

    int wq = __builtin_amdgcn_readfirstlane(wave);   // uniform wave id -> SGPR
    const float* xb = x + (size_t)b * C * HW + (size_t)(wq * 32) * HW + p0 + lane;
    const float* wrow = wTg + (size_t)(wq * 32) * CM;  // uniform base -> s_loads

    float acc[CM];
    #pragma unroll
    for (int o = 0; o < CM; ++o) acc[o] = 0.f;

    #pragma unroll 4
    for (int i = 0; i < 32; ++i) {
        float xv = xb[(size_t)i * HW];               // coalesced 256B vector load
        const float* wr = wrow + i * CM;             // uniform -> scalar loads
        #pragma unroll
        for (int o = 0; o < CM; ++o)
            acc[o] = fmaf(wr[o], xv, acc[o]);        // SGPR-operand FMA
    }

    // dump partials: per o, 64 consecutive floats -> conflict-free
    float* pq = &part[wave * CM * PB];
    #pragma unroll
    for (int o = 0; o < CM; ++o) pq[o * PB + lane] = acc[o];
    __syncthreads();

    // final: thread t owns 8 consecutive finals (one o, lanes l0..l0+7)
    int o  = tid >> 3;                 // 0..31
    int l0 = (tid & 7) * 8;
    const float* pp = &part[o * PB + l0];
    float4 f0 = *reinterpret_cast<const float4*>(pp);
    float4 f1 = *reinterpret_cast<const float4*>(pp + 4);
    #pragma unroll
    for (int q = 1; q < 4; ++q) {
        const float4 a0 = *reinterpret_cast<const float4*>(pp + q * CM * PB);
        const float4 a1 = *reinterpret_cast<const float4*>(pp + q * CM * PB + 4);
        f0.x += a0.x; f0.y += a0.y; f0.z += a0.z; f0.w += a0.w;
        f1.x += a1.x; f1.y += a1.y; f1.z += a1.z; f1.w += a1.w;
    }

    float* hb = h + ((size_t)(b * CM + o)) * HW + p0 + l0;
    *reinterpret_cast<float4*>(hb)     = f0;
    *reinterpret_cast<float4*>(hb + 4) = f1;

    // stats: sum / sumsq over this thread's 8, then over the 8 threads sharing o
    float s  = f0.x + f0.y + f0.z + f0.w + f1.x + f1.y + f1.z + f1.w;
    float s2 = f0.x * f0.x + f0.y * f0.y + f0.z * f0.z + f0.w * f0.w
             + f1.x * f1.x + f1.y * f1.y + f1.z * f1.z + f1.w * f1.w;
    #pragma unroll
    for (int off = 4; off > 0; off >>= 1) {
        s  += __shfl_down(s,  off, 8);
        s2 += __shfl_down(s2, off, 8);
    }
    if ((tid & 7) == 0) {
        part1[(size_t)o * K1B + bid]        = s;   // row o      : sums
        part1[(size_t)(o + CM) * K1B + bid] = s2;  // row CM + o : sumsq
    }
}

// ---------------- R1: parallel row-sums (64 blocks, coalesced) ----------------
__global__ __launch_bounds__(256) void k_rowsum1(
    const float* __restrict__ part1, double* __restrict__ rowsum1)
{
    __shared__ double red[256];
    int tid = threadIdx.x;
    int r = blockIdx.x;                      // 0..63
    const float* row = part1 + (size_t)r * K1B;
    double a = 0.0;
    for (int i = tid; i < K1B; i += 256) a += (double)row[i];
    red[tid] = a;
    __syncthreads();
    #pragma unroll
    for (int s = 128; s > 0; s >>= 1) {
        if (tid < s) red[tid] += red[tid + s];
        __syncthreads();
    }
    if (tid == 0) rowsum1[r] = red[0];
}

// ------- K2: BN1 (from rowsum1) + ReLU + row scan + LOCAL col scan per (plane, quarter) -------
//         quarter-local II (cross-quarter offsets folded into box kernels via qlast)
__global__ __launch_bounds__(256) void k_scan_part(
    const float* __restrict__ h, const double* __restrict__ rowsum1,
    const float* __restrict__ g1, const float* __restrict__ b1,
    float* __restrict__ II, float* __restrict__ qlast)
{
    __shared__ float buf[QR * W];   // 40 row-scanned rows, 25600 B
    int tid = threadIdx.x;
    int wave = tid >> 6, lane = tid & 63;
    int blk = blockIdx.x;           // plane*4 + q
    int plane = blk >> 2, q = blk & 3;
    int cm = plane & (CM - 1);

    double n = (double)(B * HW);
    double mean = rowsum1[cm] / n;
    double var  = rowsum1[CM + cm] / n - mean * mean;
    float inv   = (float)(1.0 / sqrt(var + 1e-5));
    float scale = g1[cm] * inv;
    float shift = b1[cm] - (float)mean * scale;

    const float* hp = h + (size_t)plane * HW + (size_t)q * QR * W;
    float* IIp = II + (size_t)plane * PLANE;

    // top border row (quarter 0 only) — independent of buf
    if (q == 0) {
        for (int e = tid; e < WP; e += 256) IIp[e] = 0.f;
    }

    // phase 1: BN+ReLU + row inclusive scan into LDS (wave-per-row shuffle scan)
    for (int y = wave; y < QR; y += 4) {
        const float* hr = hp + (size_t)y * W;
        float carry = 0.f;
        #pragma unroll
        for (int x0 = 0; x0 < W; x0 += 64) {
            int xx = x0 + lane;
            float v = (xx < W) ? fmaxf(fmaf(scale, hr[xx], shift), 0.f) : 0.f;
            #pragma unroll
            for (int off = 1; off < 64; off <<= 1) {
                float t = __shfl_up(v, off);
                if (lane >= off) v += t;
            }
            v += carry;
            if (xx < W) buf[y * W + xx] = v;
            carry = __shfl(v, 63);
        }
    }
    __syncthreads();

    // phase 2: local column scan + write II rows q*40+1 .. q*40+40 (quarter-local values)
    float* op = IIp + (size_t)(q * QR + 1) * WP;
    float* ql = qlast + ((size_t)plane * 3 + q) * WP;
    if (tid <= W) {
        float run = 0.f;
        #pragma unroll 4
        for (int r = 0; r < QR; ++r) {
            float v = 0.f;
            if (tid > 0) { run += buf[r * W + (tid - 1)]; v = run; }
            op[(size_t)r * WP + tid] = v;
            if (r == QR - 1 && q < 3) ql[tid] = v;
        }
    }
}

// ---------------- box tile machinery ----------------
struct BoxSmem {
    float D[TY][WP];      // row-interp difference rows (true II values)
    float coff[4][WP];    // cumulative cross-quarter offsets per column
    int   ru0[2][TY];     // [0]=lo, [1]=hi row coords
    int   ru1[2][TY];
    float rua[2][TY];
    int   rq0[2][TY];     // quarter index of ru0 / ru1
    int   rq1[2][TY];
    int   cv0[2][W];      // col coords ([0]=lo, [1]=hi)
    float cva[2][W];
};

__device__ inline int qidx(int row) { return row == 0 ? 0 : (row - 1) / QR; }

__device__ inline void fill_D(BoxSmem& sm, const float* __restrict__ II,
    const float* __restrict__ qlast,
    int tile, int k, int b,
    const float* __restrict__ xmin, const float* __restrict__ xmax,
    const float* __restrict__ ymin, const float* __restrict__ ymax)
{
    int tid = threadIdx.x;
    int plane = b * CM + (k >> 2);
    if (tid < 2 * TY) {
        int side = tid / TY, ty = tid % TY;
        float off = side ? (xmax[k] + 1.f) : xmin[k];
        float u = fminf(fmaxf((float)(tile * TY + ty) + off, 0.f), 160.f);
        float uf = floorf(u);
        int i0 = (int)uf;
        int i1 = min(i0 + 1, 160);
        sm.ru0[side][ty] = i0;
        sm.ru1[side][ty] = i1;
        sm.rua[side][ty] = u - uf;
        sm.rq0[side][ty] = qidx(i0);
        sm.rq1[side][ty] = qidx(i1);
    }
    // stage cumulative quarter offsets
    {
        const float* qb = qlast + (size_t)plane * 3 * WP;
        for (int v = tid; v < WP; v += 256) {
            float l0 = qb[v], l1 = qb[WP + v], l2 = qb[2 * WP + v];
            sm.coff[0][v] = 0.f;
            sm.coff[1][v] = l0;
            sm.coff[2][v] = l0 + l1;
            sm.coff[3][v] = l0 + l1 + l2;
        }
    }
    for (int e = tid; e < 2 * W; e += 256) {
        int side = e / W, xx = e % W;
        float off = side ? (ymax[k] + 1.f) : ymin[k];
        float v = fminf(fmaxf((float)xx + off, 0.f), 160.f);
        float vf = floorf(v);
        sm.cv0[side][xx] = (int)vf;
        sm.cva[side][xx] = v - vf;
    }
    __syncthreads();

    const float* P = II + (size_t)plane * PLANE;
    // TY*WP = 2576 elements; incremental (ty,v) walk, step 256 = +1 row +95 cols
    int ty = tid / WP, v = tid % WP;
    for (int e = tid; e < TY * WP; e += 256) {
        float al = sm.rua[0][ty], ah = sm.rua[1][ty];
        float lo = (P[(size_t)sm.ru0[0][ty] * WP + v] + sm.coff[sm.rq0[0][ty]][v]) * (1.f - al)
                 + (P[(size_t)sm.ru1[0][ty] * WP + v] + sm.coff[sm.rq1[0][ty]][v]) * al;
        float hi = (P[(size_t)sm.ru0[1][ty] * WP + v] + sm.coff[sm.rq0[1][ty]][v]) * (1.f - ah)
                 + (P[(size_t)sm.ru1[1][ty] * WP + v] + sm.coff[sm.rq1[1][ty]][v]) * ah;
        sm.D[ty][v] = hi - lo;
        ty += 1; v += 95;
        if (v >= WP) { v -= WP; ty += 1; }
    }
    __syncthreads();
}

__device__ inline float eval_D(const BoxSmem& sm, int ty, int xx)
{
    int   l0 = sm.cv0[0][xx];
    float la = sm.cva[0][xx];
    int   l1 = min(l0 + 1, 160);
    int   h0 = sm.cv0[1][xx];
    float ha = sm.cva[1][xx];
    int   h1 = min(h0 + 1, 160);
    const float* Dr = sm.D[ty];
    return (Dr[h0] * (1.f - ha) + Dr[h1] * ha)
         - (Dr[l0] * (1.f - la) + Dr[l1] * la);
}

// ---------------- K4: box conv -> BN2 partial stats ----------------
__global__ __launch_bounds__(256) void k_box_part(
    const float* __restrict__ II, const float* __restrict__ qlast,
    const float* __restrict__ xmin, const float* __restrict__ xmax,
    const float* __restrict__ ymin, const float* __restrict__ ymax,
    float* __restrict__ part2)
{
    __shared__ BoxSmem sm;
    __shared__ float red[4][2];
    int tile = blockIdx.x, k = blockIdx.y, b = blockIdx.z;
    fill_D(sm, II, qlast, tile, k, b, xmin, xmax, ymin, ymax);

    int tid = threadIdx.x;
    float s = 0.f, s2 = 0.f;
    // 2560 elems: o = tid + 256*i; incremental ty/xx (step = +1 row, +96 cols)
    int ty = tid / W, xx = tid % W;
    #pragma unroll
    for (int i = 0; i < TY * W / 256; ++i) {
        float v = eval_D(sm, ty, xx);
        s  += v;
        s2 += v * v;
        ty += 1; xx += 96;
        if (xx >= W) { xx -= W; ty += 1; }
    }
    #pragma unroll
    for (int off = 32; off > 0; off >>= 1) {
        s  += __shfl_down(s,  off);
        s2 += __shfl_down(s2, off);
    }
    int wave = tid >> 6, lane = tid & 63;
    if (lane == 0) { red[wave][0] = s; red[wave][1] = s2; }
    __syncthreads();
    if (tid == 0) {
        int idx = b * NTILE + tile;     // 0..39
        part2[(size_t)k * NB2 + idx]       = red[0][0] + red[1][0] + red[2][0] + red[3][0];
        part2[(size_t)(C + k) * NB2 + idx] = red[0][1] + red[1][1] + red[2][1] + red[3][1];
    }
}

// ---------------- R2: deterministic reduction -> BN2 scale/shift ----------------
__global__ __launch_bounds__(256) void k_reduce2(
    const float* __restrict__ part2, const float* __restrict__ g2,
    const float* __restrict__ b2, float* __restrict__ sc2)
{
    __shared__ double dsum[2 * C];
    int t = threadIdx.x;                 // 256 rows, one per thread
    const float4* rp = reinterpret_cast<const float4*>(part2 + (size_t)t * NB2);
    double acc = 0.0;
    #pragma unroll
    for (int i = 0; i < NB2 / 4; ++i) {
        float4 v = rp[i];
        acc += (double)v.x + (double)v.y + (double)v.z + (double)v.w;
    }
    dsum[t] = acc;
    __syncthreads();
    if (t < C) {
        double n = (double)(B * HW);
        double mean = dsum[t] / n;
        double var  = dsum[C + t] / n - mean * mean;
        float inv   = (float)(1.0 / sqrt(var + 1e-5));
        float scale = g2[t] * inv;
        sc2[t]     = scale;
        sc2[C + t] = b2[t] - (float)mean * scale;
    }
}

// ---------------- K5: box conv again, BN2, relu(x + h) ----------------
__global__ __launch_bounds__(256) void k_box_final(
    const float* __restrict__ II, const float* __restrict__ qlast,
    const float* __restrict__ x,
    const float* __restrict__ xmin, const float* __restrict__ xmax,
    const float* __restrict__ ymin, const float* __restrict__ ymax,
    const float* __restrict__ sc2, float* __restrict__ out)
{
    __shared__ BoxSmem sm;
    int tile = blockIdx.x, k = blockIdx.y, b = blockIdx.z;
    fill_D(sm, II, qlast, tile, k, b, xmin, xmax, ymin, ymax);

    int tid = threadIdx.x;
    float scale = sc2[k], shift = sc2[C + k];
    size_t base = ((size_t)(b * C + k)) * HW + (size_t)tile * TY * W;
    int ty = tid / W, xx = tid % W;
    #pragma unroll
    for (int i = 0; i < TY * W / 256; ++i) {
        float v = eval_D(sm, ty, xx);
        size_t idx = base + tid + 256 * i;      // linear -> coalesced
        out[idx] = fmaxf(x[idx] + fmaf(scale, v, shift), 0.f);
        ty += 1; xx += 96;
        if (xx >= W) { xx -= W; ty += 1; }
    }
}

// ---------------- launch ----------------
extern "C" void kernel_launch(void* const* d_in, const int* in_sizes, int n_in,
                              void* d_out, int out_size, void* d_ws, size_t ws_size,
                              hipStream_t stream)
{
    const float* x    = (const float*)d_in[0];
    const float* w1   = (const float*)d_in[1];
    const float* g1   = (const float*)d_in[2];
    const float* b1   = (const float*)d_in[3];
    const float* xmin = (const float*)d_in[4];
    const float* xmax = (const float*)d_in[5];
    const float* ymin = (const float*)d_in[6];
    const float* ymax = (const float*)d_in[7];
    const float* g2   = (const float*)d_in[8];
    const float* b2   = (const float*)d_in[9];
    float* out = (float*)d_out;

    // ws layout:
    //   [0,1024)      sc2: BN2 scale[128]| shift[128]
    //   [1280, +16K)  wTg (C*CM floats, transposed weights)
    //   [17664, +512) rowsum1 (64 doubles)
    //   [20480, +13107200)      h   (B*CM*HW floats)
    //   [+13107200, +13276672)  II  (B*CM*PLANE floats)
    //   then qlast (B*CM*3*WP floats)
    // part1 (64*1600 floats) aliases start of II (dead before k_scan_part).
    // part2 (256*40 floats) aliases start of h (h dead after k_scan_part).
    char* ws = (char*)d_ws;
    float* sc2 = (float*)ws;
    float* wTg = (float*)(ws + 1280);
    double* rowsum1 = (double*)(ws + 17664);
    float* h   = (float*)(ws + 20480);
    float* II  = (float*)(ws + 20480 + (size_t)B * CM * HW * sizeof(float));
    float* qlast = (float*)(ws + 20480 + (size_t)B * CM * HW * sizeof(float)
                               + (size_t)B * CM * PLANE * sizeof(float));
    float* part1 = II;
    float* part2 = h;

    k_transpose_w<<<dim3((C * CM + 255) / 256), 256, 0, stream>>>(w1, wTg);
    k_conv     <<<dim3(K1B), 256, 0, stream>>>(x, wTg, h, part1);
    k_rowsum1  <<<dim3(2 * CM), 256, 0, stream>>>(part1, rowsum1);
    k_scan_part<<<dim3(B * CM * 4), 256, 0, stream>>>(h, rowsum1, g1, b1, II, qlast);
    k_box_part <<<dim3(NTILE, C, B), 256, 0, stream>>>(II, qlast, xmin, xmax, ymin, ymax, part2);
    k_reduce2  <<<dim3(1), 256, 0, stream>>>(part2, g2, b2, sc2);
    k_box_final<<<dim3(NTILE, C, B), 256, 0, stream>>>(II, qlast, x, xmin, xmax, ymin, ymax,
                                                       sc2, out);
}

// Round 11
// 99.853 us; speedup vs baseline: 1.6543x; 1.0330x over previous
//
#include <hip/hip_runtime.h>
#include <cstdint>

constexpr int B  = 4;
constexpr int C  = 128;
constexpr int CM = 32;        // mid channels
constexpr int H  = 160;
constexpr int W  = 160;
constexpr int HW = H * W;     // 25600
constexpr int HP = H + 1;     // 161
constexpr int WP = W + 1;     // 161
constexpr int PLANE = HP * WP; // 25921
constexpr int TY = 16;         // rows per box tile
constexpr int NTILE = H / TY;  // 10
constexpr int PB  = 64;        // positions per conv block
constexpr int K1B = B * HW / PB; // 1600 conv blocks
constexpr int NB2 = B * NTILE; // 40 partials per out-channel
constexpr int QR = 40;         // rows per scan quarter

// ---------------- K0: transpose w1 [CM][C] -> wTg [C][CM] (16 KB, once) ----------------
__global__ __launch_bounds__(256) void k_transpose_w(
    const float* __restrict__ w1, float* __restrict__ wTg)
{
    int t = blockIdx.x * 256 + threadIdx.x;    // 4096 elements
    if (t < C * CM) {
        int o = t / C, c = t % C;
        wTg[c * CM + o] = w1[t];
    }
}

// ------- K1: 1x1 conv, split-C: wave q owns c in [32q,32q+32), 64 pos/block -------
__global__ __launch_bounds__(256) void k_conv(
    const float* __restrict__ x, const float* __restrict__ wTg,
    float* __restrict__ h, float* __restrict__ part1)
{
    __shared__ float part[4 * CM * PB];   // 32 KB: [q][o][lane]
    int tid = threadIdx.x;
    int wave = tid >> 6, lane = tid & 63;
    int bid = blockIdx.x;                 // 1600 blocks; 400 per batch image
    int b = bid / 400;
    int p0 = (bid % 400) * PB;

    int wq = __builtin_amdgcn_readfirstlane(wave);   // uniform wave id -> SGPR
    const float* xb = x + (size_t)b * C * HW + (size_t)(wq * 32) * HW + p0 + lane;
    const float* wrow = wTg + (size_t)(wq * 32) * CM;  // uniform base -> s_loads

    float acc[CM];
    #pragma unroll
    for (int o = 0; o < CM; ++o) acc[o] = 0.f;

    #pragma unroll 4
    for (int i = 0; i < 32; ++i) {
        float xv = xb[(size_t)i * HW];               // coalesced 256B vector load
        const float* wr = wrow + i * CM;             // uniform -> scalar loads
        #pragma unroll
        for (int o = 0; o < CM; ++o)
            acc[o] = fmaf(wr[o], xv, acc[o]);        // SGPR-operand FMA
    }

    float* pq = &part[wave * CM * PB];
    #pragma unroll
    for (int o = 0; o < CM; ++o) pq[o * PB + lane] = acc[o];
    __syncthreads();

    // final: thread t owns 8 consecutive finals (one o, lanes l0..l0+7)
    int o  = tid >> 3;                 // 0..31
    int l0 = (tid & 7) * 8;
    const float* pp = &part[o * PB + l0];
    float4 f0 = *reinterpret_cast<const float4*>(pp);
    float4 f1 = *reinterpret_cast<const float4*>(pp + 4);
    #pragma unroll
    for (int q = 1; q < 4; ++q) {
        const float4 a0 = *reinterpret_cast<const float4*>(pp + q * CM * PB);
        const float4 a1 = *reinterpret_cast<const float4*>(pp + q * CM * PB + 4);
        f0.x += a0.x; f0.y += a0.y; f0.z += a0.z; f0.w += a0.w;
        f1.x += a1.x; f1.y += a1.y; f1.z += a1.z; f1.w += a1.w;
    }

    float* hb = h + ((size_t)(b * CM + o)) * HW + p0 + l0;
    *reinterpret_cast<float4*>(hb)     = f0;
    *reinterpret_cast<float4*>(hb + 4) = f1;

    float s  = f0.x + f0.y + f0.z + f0.w + f1.x + f1.y + f1.z + f1.w;
    float s2 = f0.x * f0.x + f0.y * f0.y + f0.z * f0.z + f0.w * f0.w
             + f1.x * f1.x + f1.y * f1.y + f1.z * f1.z + f1.w * f1.w;
    #pragma unroll
    for (int off = 4; off > 0; off >>= 1) {
        s  += __shfl_down(s,  off, 8);
        s2 += __shfl_down(s2, off, 8);
    }
    if ((tid & 7) == 0) {
        part1[(size_t)o * K1B + bid]        = s;   // row o      : sums
        part1[(size_t)(o + CM) * K1B + bid] = s2;  // row CM + o : sumsq
    }
}

// ---------------- R1: parallel row-sums (64 blocks, coalesced) ----------------
__global__ __launch_bounds__(256) void k_rowsum1(
    const float* __restrict__ part1, double* __restrict__ rowsum1)
{
    __shared__ double red[256];
    int tid = threadIdx.x;
    int r = blockIdx.x;                      // 0..63
    const float* row = part1 + (size_t)r * K1B;
    double a = 0.0;
    for (int i = tid; i < K1B; i += 256) a += (double)row[i];
    red[tid] = a;
    __syncthreads();
    #pragma unroll
    for (int s = 128; s > 0; s >>= 1) {
        if (tid < s) red[tid] += red[tid + s];
        __syncthreads();
    }
    if (tid == 0) rowsum1[r] = red[0];
}

// ------- K2: BN1 (from rowsum1) + ReLU + row scan + LOCAL col scan per (plane, quarter) -------
__global__ __launch_bounds__(256) void k_scan_part(
    const float* __restrict__ h, const double* __restrict__ rowsum1,
    const float* __restrict__ g1, const float* __restrict__ b1,
    float* __restrict__ II, float* __restrict__ qlast)
{
    __shared__ float buf[QR * W];   // 40 row-scanned rows, 25600 B
    int tid = threadIdx.x;
    int wave = tid >> 6, lane = tid & 63;
    int blk = blockIdx.x;           // plane*4 + q
    int plane = blk >> 2, q = blk & 3;
    int cm = plane & (CM - 1);

    double n = (double)(B * HW);
    double mean = rowsum1[cm] / n;
    double var  = rowsum1[CM + cm] / n - mean * mean;
    float inv   = (float)(1.0 / sqrt(var + 1e-5));
    float scale = g1[cm] * inv;
    float shift = b1[cm] - (float)mean * scale;

    const float* hp = h + (size_t)plane * HW + (size_t)q * QR * W;
    float* IIp = II + (size_t)plane * PLANE;

    if (q == 0) {
        for (int e = tid; e < WP; e += 256) IIp[e] = 0.f;
    }

    for (int y = wave; y < QR; y += 4) {
        const float* hr = hp + (size_t)y * W;
        float carry = 0.f;
        #pragma unroll
        for (int x0 = 0; x0 < W; x0 += 64) {
            int xx = x0 + lane;
            float v = (xx < W) ? fmaxf(fmaf(scale, hr[xx], shift), 0.f) : 0.f;
            #pragma unroll
            for (int off = 1; off < 64; off <<= 1) {
                float t = __shfl_up(v, off);
                if (lane >= off) v += t;
            }
            v += carry;
            if (xx < W) buf[y * W + xx] = v;
            carry = __shfl(v, 63);
        }
    }
    __syncthreads();

    float* op = IIp + (size_t)(q * QR + 1) * WP;
    float* ql = qlast + ((size_t)plane * 3 + q) * WP;
    if (tid <= W) {
        float run = 0.f;
        #pragma unroll 4
        for (int r = 0; r < QR; ++r) {
            float v = 0.f;
            if (tid > 0) { run += buf[r * W + (tid - 1)]; v = run; }
            op[(size_t)r * WP + tid] = v;
            if (r == QR - 1 && q < 3) ql[tid] = v;
        }
    }
}

// ---------------- box tile machinery ----------------
struct BoxSmem {
    float D[TY][WP];      // row-interp difference rows (true II values)
    float coff[4][WP];    // cumulative cross-quarter offsets per column
    int   ru0[2][TY];     // [0]=lo, [1]=hi row coords
    int   ru1[2][TY];
    float rua[2][TY];
    int   rq0[2][TY];     // quarter index of ru0 / ru1
    int   rq1[2][TY];
};

__device__ inline int qidx(int row) { return row == 0 ? 0 : (row - 1) / QR; }

__device__ inline void fill_D(BoxSmem& sm, const float* __restrict__ II,
    const float* __restrict__ qlast,
    int tile, int k, int b,
    const float* __restrict__ xmin, const float* __restrict__ xmax)
{
    int tid = threadIdx.x;
    int plane = b * CM + (k >> 2);
    if (tid < 2 * TY) {
        int side = tid / TY, ty = tid % TY;
        float off = side ? (xmax[k] + 1.f) : xmin[k];
        float u = fminf(fmaxf((float)(tile * TY + ty) + off, 0.f), 160.f);
        float uf = floorf(u);
        int i0 = (int)uf;
        int i1 = min(i0 + 1, 160);
        sm.ru0[side][ty] = i0;
        sm.ru1[side][ty] = i1;
        sm.rua[side][ty] = u - uf;
        sm.rq0[side][ty] = qidx(i0);
        sm.rq1[side][ty] = qidx(i1);
    }
    {
        const float* qb = qlast + (size_t)plane * 3 * WP;
        for (int v = tid; v < WP; v += 256) {
            float l0 = qb[v], l1 = qb[WP + v], l2 = qb[2 * WP + v];
            sm.coff[0][v] = 0.f;
            sm.coff[1][v] = l0;
            sm.coff[2][v] = l0 + l1;
            sm.coff[3][v] = l0 + l1 + l2;
        }
    }
    __syncthreads();

    const float* P = II + (size_t)plane * PLANE;
    int ty = tid / WP, v = tid % WP;
    for (int e = tid; e < TY * WP; e += 256) {
        float al = sm.rua[0][ty], ah = sm.rua[1][ty];
        float lo = (P[(size_t)sm.ru0[0][ty] * WP + v] + sm.coff[sm.rq0[0][ty]][v]) * (1.f - al)
                 + (P[(size_t)sm.ru1[0][ty] * WP + v] + sm.coff[sm.rq1[0][ty]][v]) * al;
        float hi = (P[(size_t)sm.ru0[1][ty] * WP + v] + sm.coff[sm.rq0[1][ty]][v]) * (1.f - ah)
                 + (P[(size_t)sm.ru1[1][ty] * WP + v] + sm.coff[sm.rq1[1][ty]][v]) * ah;
        sm.D[ty][v] = hi - lo;
        ty += 1; v += 95;
        if (v >= WP) { v -= WP; ty += 1; }
    }
    __syncthreads();
}

// per-column hoisted coords (computed once per thread, registers)
struct ColW { int l0, l1, h0, h1; float la, ha; };

__device__ inline ColW mk_colw(int xx, float ylo, float yhi)
{
    ColW c;
    float v = fminf(fmaxf((float)xx + ylo, 0.f), 160.f);
    float vf = floorf(v);
    c.l0 = (int)vf; c.la = v - vf; c.l1 = min(c.l0 + 1, 160);
    v = fminf(fmaxf((float)xx + yhi, 0.f), 160.f);
    vf = floorf(v);
    c.h0 = (int)vf; c.ha = v - vf; c.h1 = min(c.h0 + 1, 160);
    return c;
}

__device__ inline float eval_col(const BoxSmem& sm, int ty, const ColW& c)
{
    const float* Dr = sm.D[ty];
    return (Dr[c.h0] * (1.f - c.ha) + Dr[c.h1] * c.ha)
         - (Dr[c.l0] * (1.f - c.la) + Dr[c.l1] * c.la);
}

// ---------------- K4: box conv -> BN2 partial stats ----------------
__global__ __launch_bounds__(256) void k_box_part(
    const float* __restrict__ II, const float* __restrict__ qlast,
    const float* __restrict__ xmin, const float* __restrict__ xmax,
    const float* __restrict__ ymin, const float* __restrict__ ymax,
    float* __restrict__ part2)
{
    __shared__ BoxSmem sm;
    __shared__ float red[4][2];
    int tile = blockIdx.x, k = blockIdx.y, b = blockIdx.z;
    fill_D(sm, II, qlast, tile, k, b, xmin, xmax);

    int tid = threadIdx.x;
    float s = 0.f, s2 = 0.f;
    if (tid < W) {
        ColW c = mk_colw(tid, ymin[k], ymax[k] + 1.f);
        #pragma unroll
        for (int ty = 0; ty < TY; ++ty) {
            float v = eval_col(sm, ty, c);
            s  += v;
            s2 += v * v;
        }
    }
    #pragma unroll
    for (int off = 32; off > 0; off >>= 1) {
        s  += __shfl_down(s,  off);
        s2 += __shfl_down(s2, off);
    }
    int wave = tid >> 6, lane = tid & 63;
    if (lane == 0) { red[wave][0] = s; red[wave][1] = s2; }
    __syncthreads();
    if (tid == 0) {
        int idx = b * NTILE + tile;     // 0..39
        part2[(size_t)k * NB2 + idx]       = red[0][0] + red[1][0] + red[2][0] + red[3][0];
        part2[(size_t)(C + k) * NB2 + idx] = red[0][1] + red[1][1] + red[2][1] + red[3][1];
    }
}

// ---------------- R2: deterministic reduction -> BN2 scale/shift ----------------
__global__ __launch_bounds__(256) void k_reduce2(
    const float* __restrict__ part2, const float* __restrict__ g2,
    const float* __restrict__ b2, float* __restrict__ sc2)
{
    __shared__ double dsum[2 * C];
    int t = threadIdx.x;                 // 256 rows, one per thread
    const float4* rp = reinterpret_cast<const float4*>(part2 + (size_t)t * NB2);
    double acc = 0.0;
    #pragma unroll
    for (int i = 0; i < NB2 / 4; ++i) {
        float4 v = rp[i];
        acc += (double)v.x + (double)v.y + (double)v.z + (double)v.w;
    }
    dsum[t] = acc;
    __syncthreads();
    if (t < C) {
        double n = (double)(B * HW);
        double mean = dsum[t] / n;
        double var  = dsum[C + t] / n - mean * mean;
        float inv   = (float)(1.0 / sqrt(var + 1e-5));
        float scale = g2[t] * inv;
        sc2[t]     = scale;
        sc2[C + t] = b2[t] - (float)mean * scale;
    }
}

// ---------------- K5: box conv again, BN2, relu(x + h) ----------------
__global__ __launch_bounds__(256) void k_box_final(
    const float* __restrict__ II, const float* __restrict__ qlast,
    const float* __restrict__ x,
    const float* __restrict__ xmin, const float* __restrict__ xmax,
    const float* __restrict__ ymin, const float* __restrict__ ymax,
    const float* __restrict__ sc2, float* __restrict__ out)
{
    __shared__ BoxSmem sm;
    int tile = blockIdx.x, k = blockIdx.y, b = blockIdx.z;
    fill_D(sm, II, qlast, tile, k, b, xmin, xmax);

    int tid = threadIdx.x;
    float scale = sc2[k], shift = sc2[C + k];
    size_t base = ((size_t)(b * C + k)) * HW + (size_t)tile * TY * W;
    if (tid < W) {
        ColW c = mk_colw(tid, ymin[k], ymax[k] + 1.f);
        #pragma unroll
        for (int ty = 0; ty < TY; ++ty) {
            float v = eval_col(sm, ty, c);
            size_t idx = base + (size_t)ty * W + tid;   // row-contiguous
            out[idx] = fmaxf(x[idx] + fmaf(scale, v, shift), 0.f);
        }
    }
}

// ---------------- launch ----------------
extern "C" void kernel_launch(void* const* d_in, const int* in_sizes, int n_in,
                              void* d_out, int out_size, void* d_ws, size_t ws_size,
                              hipStream_t stream)
{
    const float* x    = (const float*)d_in[0];
    const float* w1   = (const float*)d_in[1];
    const float* g1   = (const float*)d_in[2];
    const float* b1   = (const float*)d_in[3];
    const float* xmin = (const float*)d_in[4];
    const float* xmax = (const float*)d_in[5];
    const float* ymin = (const float*)d_in[6];
    const float* ymax = (const float*)d_in[7];
    const float* g2   = (const float*)d_in[8];
    const float* b2   = (const float*)d_in[9];
    float* out = (float*)d_out;

    char* ws = (char*)d_ws;
    float* sc2 = (float*)ws;
    float* wTg = (float*)(ws + 1280);
    double* rowsum1 = (double*)(ws + 17664);
    float* h   = (float*)(ws + 20480);
    float* II  = (float*)(ws + 20480 + (size_t)B * CM * HW * sizeof(float));
    float* qlast = (float*)(ws + 20480 + (size_t)B * CM * HW * sizeof(float)
                               + (size_t)B * CM * PLANE * sizeof(float));
    float* part1 = II;   // dead before k_scan_part writes II
    float* part2 = h;    // h dead after k_scan_part

    k_transpose_w<<<dim3((C * CM + 255) / 256), 256, 0, stream>>>(w1, wTg);
    k_conv     <<<dim3(K1B), 256, 0, stream>>>(x, wTg, h, part1);
    k_rowsum1  <<<dim3(2 * CM), 256, 0, stream>>>(part1, rowsum1);
    k_scan_part<<<dim3(B * CM * 4), 256, 0, stream>>>(h, rowsum1, g1, b1, II, qlast);
    k_box_part <<<dim3(NTILE, C, B), 256, 0, stream>>>(II, qlast, xmin, xmax, ymin, ymax, part2);
    k_reduce2  <<<dim3(1), 256, 0, stream>>>(part2, g2, b2, sc2);
    k_box_final<<<dim3(NTILE, C, B), 256, 0, stream>>>(II, qlast, x, xmin, xmax, ymin, ymax,
                                                       sc2, out);
}